// Round 1
// 153.943 us; speedup vs baseline: 1.0099x; 1.0099x over previous
//
#include <hip/hip_runtime.h>
#include <math.h>

// ---------------------------------------------------------------------------
// YOLOv7 loss on MI355X — single-launch version, round 1 (parallel assignment).
// Inputs (setup_inputs order):
//   d_in[0] p0: (16,255,80,80) f32
//   d_in[1] p1: (16,255,40,40) f32
//   d_in[2] p2: (16,255,20,20) f32
//   d_in[3] targets: (16,12,6) f32  [nb, cls, cx, cy, gw, gh]
//   d_in[4] image_size: (2,) f32
// Output: 4 f32 scalars [total, lbox*3.54, lobj*64.3, lcls*37.4]
//
// Structure (190 blocks, all co-resident on 256 CUs):
//   blocks 0..143   : per-(scale,b,a) objectness-plane softplus partial sum
//                     (float4 loads, fast __expf/__logf softplus)
//   blocks 144..188 : assignment blocks — ONE PER (scale,anchor,offset).
//                     Each thread handles exactly one target (192 targets,
//                     3 waves), so a matched thread's 85 scattered loads are
//                     a single overlapped latency round. 45 CUs active vs the
//                     previous 3 → removes the serial per-thread combo walk
//                     that dominated the old kernel's critical path.
//   block 189       : finalizer — spins on per-block magic flags (device-scope
//                     atomicOr reads; poison 0xAA != MAGIC so NO init kernel
//                     is needed), gathers partials, writes the 4 outputs.
//
// All cross-block values are written with device-scope atomicExch and read
// with atomicAdd(p,0) — coherent across XCDs. __threadfence() orders each
// block's partial writes before its flag write.
//
// lobj identity: mean(BCE(x,tobj)) = (sum softplus(x) - sum_matched x*clip(iou,0))/N
// ---------------------------------------------------------------------------

#define NT      192               // 16*12 targets
#define NOFF    5
#define NANCH   3
#define THRESH  4.0f
#define NB      16
#define NCLS    80
#define NPLANE  144               // 3 scales * 16 batch * 3 anchors
#define NAPS    (NANCH*NOFF)      // assignment blocks per scale = 15
#define NASSIGN (3*NAPS)          // 45
#define NWORK   (NPLANE + NASSIGN) // 189 worker blocks (have flags)
#define NBLK    (NWORK + 1)       // 190 total (last = finalizer)
#define MAGIC   0x5EED0001
// ws word layout (floats):
#define WS_FLAG   0               // [0..188] int flags
#define WS_DENSE  256             // [256..399] float: per-plane softplus partial
#define WS_ASSIGN 448             // [448..627] float: per-assign-block {n,corr,lbox,lcls}

__device__ __constant__ int   c_H[3]  = {80, 40, 20};
__device__ __constant__ int   c_W[3]  = {80, 40, 20};
__device__ __constant__ int   c_HW[3] = {6400, 1600, 400};
__device__ __constant__ float c_anch[18] = {10,13, 16,30, 33,23,
                                            30,61, 62,45, 59,119,
                                            116,90, 156,198, 373,326};
__device__ __constant__ float c_offs[10] = {0,0, 1,0, 0,1, -1,0, 0,-1};

__device__ __forceinline__ float sigmoidf(float x) {
    return 1.0f / (1.0f + __expf(-x));
}
__device__ __forceinline__ float softplusf(float x) {
    // fmax(x,0) + log1p(exp(-|x|)) with HW exp2/log2 — |err| ~1e-6 rel
    return fmaxf(x, 0.0f) + __logf(1.0f + __expf(-fabsf(x)));
}

__global__ void __launch_bounds__(256)
k_fused(const float* __restrict__ p0,
        const float* __restrict__ p1,
        const float* __restrict__ p2,
        const float* __restrict__ targets,
        const float* __restrict__ image_size,
        float* __restrict__ ws,
        float* __restrict__ out) {
    const int bid = blockIdx.x;
    const int tid = threadIdx.x;
    int* iws = (int*)ws;

    __shared__ float s_red[8];        // dense-block reduction scratch
    __shared__ float s_t[NT * 6];     // targets (assign blocks)
    __shared__ float s_isz[2];
    __shared__ float s_a[4][4];       // assign-block 4-wave partials
    __shared__ float s_sp[3];         // finalizer per-scale softplus sums
    __shared__ float s_as[3][4];      // finalizer per-scale assign sums

    if (bid < NPLANE) {
        // ---- dense objectness softplus over one (scale,b,a) plane ----
        if (tid < 8) s_red[tid] = 0.0f;
        const int scale = bid / (NB * NANCH);
        const int rem   = bid % (NB * NANCH);
        const int b     = rem / NANCH;
        const int a     = rem % NANCH;
        const int HW    = c_HW[scale];
        const float* p  = (scale == 0) ? p0 : ((scale == 1) ? p1 : p2);
        const float4* plane = (const float4*)(p + (size_t)b * 255 * HW
                                                + (size_t)(a * 85 + 4) * HW);
        const int n4 = HW >> 2;
        float s = 0.0f;
        for (int i = tid; i < n4; i += 256) {
            const float4 v = plane[i];
            s += softplusf(v.x) + softplusf(v.y) + softplusf(v.z) + softplusf(v.w);
        }
        for (int off = 32; off > 0; off >>= 1) s += __shfl_down(s, off, 64);
        if ((tid & 63) == 0) s_red[tid >> 6] = s;
        __syncthreads();
        if (tid == 0) {
            const float part = s_red[0] + s_red[1] + s_red[2] + s_red[3];
            atomicExch(&ws[WS_DENSE + bid], part);
            __threadfence();
            atomicExch(&iws[WS_FLAG + bid], MAGIC);
        }
    } else if (bid < NWORK) {
        // ---- one (scale, anchor, offset): 192 targets, one per thread ----
        const int aid   = bid - NPLANE;
        const int scale = aid / NAPS;
        const int chunk = aid % NAPS;
        const int a     = chunk / NOFF;
        const int o     = chunk % NOFF;

        if (tid == 0) { s_isz[0] = image_size[0]; s_isz[1] = image_size[1]; }
        for (int k = tid; k < NT * 6; k += 256) s_t[k] = targets[k];
        __syncthreads();

        const int H = c_H[scale], W = c_W[scale];
        const int HW = c_HW[scale];
        const float gx_mul = (float)W / s_isz[1];
        const float gy_mul = (float)H / s_isz[0];
        const float* p = (scale == 0) ? p0 : ((scale == 1) ? p1 : p2);

        float n_loc = 0.0f;
        float corr_loc = 0.0f, lbox_loc = 0.0f, lcls_loc = 0.0f;

        if (tid < NT) {
            const int t = tid;

            const float cx = s_t[t*6 + 2] * gx_mul;
            const float cy = s_t[t*6 + 3] * gy_mul;
            const float gw = s_t[t*6 + 4] * gx_mul;
            const float gh = s_t[t*6 + 5] * gy_mul;

            const float gxf = cx - c_offs[o*2 + 0];
            const float gyf = cy - c_offs[o*2 + 1];
            const bool in_grid = (gxf >= 0.0f && gxf < (float)W &&
                                  gyf >= 0.0f && gyf < (float)H);

            const float aw = c_anch[(scale*3 + a)*2 + 0] * gx_mul;
            const float ah = c_anch[(scale*3 + a)*2 + 1] * gy_mul;
            const float rx = gw / aw, ry = gh / ah;
            const float mr = fmaxf(fmaxf(rx, 1.0f/rx), fmaxf(ry, 1.0f/ry));

            if (in_grid && (mr < THRESH)) {
                n_loc = 1.0f;

                const int b   = (int)s_t[t*6 + 0];
                const int cls = (int)s_t[t*6 + 1];
                const int gi  = (int)gxf;
                const int gj  = (int)gyf;
                const float tbx = cx - (float)gi;
                const float tby = cy - (float)gj;

                const float* base = p + (size_t)b * 255 * HW
                                      + (size_t)(a * 85) * HW
                                      + (size_t)gj * W + gi;

                const float ps0 = base[0];
                const float ps1 = base[(size_t)HW];
                const float ps2 = base[2*(size_t)HW];
                const float ps3 = base[3*(size_t)HW];
                const float ps4 = base[4*(size_t)HW];

                const float px = sigmoidf(ps0) * 3.0f - 1.0f;
                const float py = sigmoidf(ps1) * 3.0f - 1.0f;
                float pw = sigmoidf(ps2) * 2.0f; pw = pw * pw * aw;
                float ph = sigmoidf(ps3) * 2.0f; ph = ph * ph * ah;

                const float eps = 1e-7f;
                const float b1x1 = px - pw*0.5f, b1x2 = px + pw*0.5f;
                const float b1y1 = py - ph*0.5f, b1y2 = py + ph*0.5f;
                const float b2x1 = tbx - gw*0.5f, b2x2 = tbx + gw*0.5f;
                const float b2y1 = tby - gh*0.5f, b2y2 = tby + gh*0.5f;
                const float iw = fmaxf(fminf(b1x2,b2x2) - fmaxf(b1x1,b2x1), 0.0f);
                const float ih = fmaxf(fminf(b1y2,b2y2) - fmaxf(b1y1,b2y1), 0.0f);
                const float inter = iw * ih;
                const float uni   = pw*ph + gw*gh - inter + eps;
                const float iou   = inter / uni;
                const float cwid  = fmaxf(b1x2,b2x2) - fminf(b1x1,b2x1);
                const float chgt  = fmaxf(b1y2,b2y2) - fminf(b1y1,b2y1);
                const float c2    = cwid*cwid + chgt*chgt + eps;
                const float dx    = b2x1 + b2x2 - b1x1 - b1x2;
                const float dy    = b2y1 + b2y2 - b1y1 - b1y2;
                const float rho2  = (dx*dx + dy*dy) * 0.25f;
                const float dv    = atanf(gw / (gh + eps)) - atanf(pw / (ph + eps));
                const float v     = 0.4052847345693511f * dv * dv;  // 4/pi^2
                const float alpha = v / (v - iou + (1.0f + eps));
                const float ciou  = iou - (rho2 / c2 + v * alpha);

                lbox_loc = 1.0f - ciou;
                corr_loc = ps4 * fmaxf(ciou, 0.0f);

                float ls = 0.0f;
                const float* cb = base + 5*(size_t)HW;
                for (int c = 0; c < NCLS; c++) {
                    const float x  = cb[(size_t)c * HW];
                    const float tv = (c == cls - 1) ? 1.0f : 0.0f;
                    ls += fmaxf(x, 0.0f) - x * tv + __logf(1.0f + __expf(-fabsf(x)));
                }
                lcls_loc = ls;
            }
        }

        // block reduction of the 4 partials via wave shuffles + LDS
        for (int off = 32; off > 0; off >>= 1) {
            n_loc    += __shfl_down(n_loc,    off, 64);
            corr_loc += __shfl_down(corr_loc, off, 64);
            lbox_loc += __shfl_down(lbox_loc, off, 64);
            lcls_loc += __shfl_down(lcls_loc, off, 64);
        }
        if ((tid & 63) == 0) {
            const int w = tid >> 6;
            s_a[w][0] = n_loc;    s_a[w][1] = corr_loc;
            s_a[w][2] = lbox_loc; s_a[w][3] = lcls_loc;
        }
        __syncthreads();
        if (tid == 0) {
            const int basei = WS_ASSIGN + aid * 4;
            atomicExch(&ws[basei + 0], s_a[0][0]+s_a[1][0]+s_a[2][0]+s_a[3][0]);
            atomicExch(&ws[basei + 1], s_a[0][1]+s_a[1][1]+s_a[2][1]+s_a[3][1]);
            atomicExch(&ws[basei + 2], s_a[0][2]+s_a[1][2]+s_a[2][2]+s_a[3][2]);
            atomicExch(&ws[basei + 3], s_a[0][3]+s_a[1][3]+s_a[2][3]+s_a[3][3]);
            __threadfence();
            atomicExch(&iws[WS_FLAG + bid], MAGIC);
        }
    } else {
        // ---- finalizer: wait for all worker flags, then reduce ----
        if (tid < 3)  s_sp[tid] = 0.0f;
        if (tid < 12) ((float*)s_as)[tid] = 0.0f;
        if (tid < NWORK) {
            while (atomicOr(&iws[WS_FLAG + tid], 0) != MAGIC) {
                __builtin_amdgcn_s_sleep(1);
            }
        }
        __syncthreads();
        // gather dense partials -> per-scale LDS sums
        if (tid < NPLANE) {
            const float v = atomicAdd(&ws[WS_DENSE + tid], 0.0f);
            atomicAdd(&s_sp[tid / (NB * NANCH)], v);
        }
        // gather assignment partials -> per-scale LDS sums
        if (tid < NASSIGN) {
            const int s = tid / NAPS;
            const int basei = WS_ASSIGN + tid * 4;
            atomicAdd(&s_as[s][0], atomicAdd(&ws[basei + 0], 0.0f));
            atomicAdd(&s_as[s][1], atomicAdd(&ws[basei + 1], 0.0f));
            atomicAdd(&s_as[s][2], atomicAdd(&ws[basei + 2], 0.0f));
            atomicAdd(&s_as[s][3], atomicAdd(&ws[basei + 3], 0.0f));
        }
        __syncthreads();
        if (tid == 0) {
            const float bal[3] = {4.0f, 1.0f, 0.4f};
            float lobj = 0.0f, lbox = 0.0f, lcls = 0.0f;
            #pragma unroll
            for (int i = 0; i < 3; i++) {
                const float n    = s_as[i][0];
                const float corr = s_as[i][1];
                const float lbx  = s_as[i][2];
                const float lcl  = s_as[i][3];
                const float cnt  = (float)(NB * NANCH * c_HW[i]);
                lobj += (s_sp[i] - corr) / cnt * bal[i];
                if (n > 0.5f) {
                    lbox += lbx / n;
                    lcls += lcl / (n * (float)NCLS);
                }
            }
            lbox *= 3.54f;
            lobj *= 64.3f;
            lcls *= 37.4f;
            out[0] = lbox + lobj + lcls;
            out[1] = lbox;
            out[2] = lobj;
            out[3] = lcls;
        }
    }
}

extern "C" void kernel_launch(void* const* d_in, const int* in_sizes, int n_in,
                              void* d_out, int out_size, void* d_ws, size_t ws_size,
                              hipStream_t stream) {
    const float* p0  = (const float*)d_in[0];
    const float* p1  = (const float*)d_in[1];
    const float* p2  = (const float*)d_in[2];
    const float* tgt = (const float*)d_in[3];
    const float* isz = (const float*)d_in[4];
    float* out = (float*)d_out;
    float* ws  = (float*)d_ws;

    k_fused<<<NBLK, 256, 0, stream>>>(p0, p1, p2, tgt, isz, ws, out);
}